// Round 11
// baseline (201.857 us; speedup 1.0000x reference)
//
#include <hip/hip_runtime.h>
#include <math.h>

// ---------------------------------------------------------------------------
// AttentionBlock: GN(4,256) -> QKV 1x1 conv -> 2-head attn (N=1024, hd=128)
// -> proj -> +residual.  B=16, C=256, H=W=32 (N=1024), fp32 in/out.
// R11: attn back to LDS-staged 16x16x32 (R6 layouts, R3 re-frag) but grid
// 1024 (32-row q-tiles) + 48 KB LDS (K dbuf + V single, R8 barriers) ->
// 3 blocks/CU, 12 waves/CU. prep/qkv_fused/proj unchanged.
// ---------------------------------------------------------------------------

typedef __attribute__((ext_vector_type(8))) short bf16x8;    // 8 bf16 = 4 VGPRs
typedef __attribute__((ext_vector_type(4))) float f32x4;

__device__ __forceinline__ unsigned short f2bf(float f) {   // RNE-ish
    union { float f; unsigned u; } v; v.f = f;
    return (unsigned short)((v.u + 0x7FFFu + ((v.u >> 16) & 1u)) >> 16);
}
__device__ __forceinline__ unsigned bfbits(float f) {       // +half (round up)
    union { float f; unsigned u; } v; v.f = f;
    return v.u + 0x8000u;
}
// pack two floats -> (bf(a) | bf(b)<<16), rounded (3 VALU)
__device__ __forceinline__ unsigned packbf(float a, float b) {
    return __builtin_amdgcn_perm(bfbits(b), bfbits(a), 0x07060302u);
}
// truncating pack (1 VALU op) -- for softmax weights (<=0.8% rel err)
__device__ __forceinline__ unsigned packtr(float a, float b) {
    union { float f; unsigned u; } va, vb; va.f = a; vb.f = b;
    return __builtin_amdgcn_perm(vb.u, va.u, 0x07060302u);
}

__device__ __forceinline__ void gload_lds16(const void* g, void* l) {
    __builtin_amdgcn_global_load_lds(
        (const __attribute__((address_space(1))) unsigned int*)g,
        (__attribute__((address_space(3))) unsigned int*)l, 16, 0, 0);
}

// ------------------------------------------- prep: weights->bf16 + GN stats
__global__ __launch_bounds__(256) void prep(const float* __restrict__ wq,
                                            const float* __restrict__ wk,
                                            const float* __restrict__ wv,
                                            const float* __restrict__ wp,
                                            unsigned short* __restrict__ oq,
                                            unsigned short* __restrict__ ok,
                                            unsigned short* __restrict__ ov,
                                            unsigned short* __restrict__ op,
                                            const float* __restrict__ x,
                                            float* __restrict__ acc) {
    int bid = blockIdx.x;
    if (bid < 256) {
        int idx = bid * 1024 + threadIdx.x * 4;
        int which = idx >> 16, i = idx & 65535;
        const float* src = (which == 0) ? wq : (which == 1) ? wk : (which == 2) ? wv : wp;
        unsigned short* dst = (which == 0) ? oq : (which == 1) ? ok : (which == 2) ? ov : op;
        // fold softmax scale 512^-0.5 AND log2(e) into wq (softmax uses exp2)
        float scl = (which == 0) ? (0.044194173824159216f * 1.4426950408889634f) : 1.0f;
        float4 v = *(const float4*)(src + i);
        ushort4 o;
        o.x = f2bf(v.x * scl); o.y = f2bf(v.y * scl);
        o.z = f2bf(v.z * scl); o.w = f2bf(v.w * scl);
        *(ushort4*)(dst + i) = o;
    } else {
        int bid2 = bid - 256;                  // [0,512)
        int bg = bid2 >> 3, ch = bid2 & 7;
        const float4* xp = (const float4*)(x + (size_t)bg * 65536 + ch * 8192);
        float s = 0.f, s2 = 0.f;
#pragma unroll
        for (int i = 0; i < 8; i++) {
            float4 v = xp[threadIdx.x + i * 256];
            s  += v.x + v.y + v.z + v.w;
            s2 += v.x * v.x + v.y * v.y + v.z * v.z + v.w * v.w;
        }
        for (int m = 1; m < 64; m <<= 1) { s += __shfl_xor(s, m); s2 += __shfl_xor(s2, m); }
        __shared__ float ls[8];
        int w = threadIdx.x >> 6, lane = threadIdx.x & 63;
        if (lane == 0) { ls[w] = s; ls[4 + w] = s2; }
        __syncthreads();
        if (threadIdx.x == 0) {
            acc[bg * 16 + ch * 2]     = ls[0] + ls[1] + ls[2] + ls[3];
            acc[bg * 16 + ch * 2 + 1] = ls[4] + ls[5] + ls[6] + ls[7];
        }
    }
}

// --------------------------------------------------- QKV GEMM fused with GN
__global__ __launch_bounds__(256) void qkv_fused(const float* __restrict__ x,
                                                 const float* __restrict__ acc,
                                                 const float* __restrict__ gnw,
                                                 const float* __restrict__ gnb,
                                                 const unsigned short* __restrict__ wqb,
                                                 const unsigned short* __restrict__ wkb,
                                                 const unsigned short* __restrict__ wvb,
                                                 unsigned short* __restrict__ qt,
                                                 unsigned short* __restrict__ kt,
                                                 unsigned short* __restrict__ vv) {
    int b = blockIdx.z, half = blockIdx.y, nx = blockIdx.x;
    int n0 = nx * 64;
    int t = threadIdx.x, w = t >> 6, lane = t & 63, quad = lane >> 4, c4 = lane & 15;
    __shared__ __align__(16) unsigned short xl[17408];   // p1: [64][264]; p2: Q-et@0, K-et@8704
    __shared__ __align__(16) unsigned short ebuf[9216];  // V-et2 [128][72]
    __shared__ float gs[8];
    if (t < 4) {
        float s0 = 0.f, s1 = 0.f;
#pragma unroll
        for (int p = 0; p < 8; p++) {
            s0 += acc[(b * 4 + t) * 16 + p * 2];
            s1 += acc[(b * 4 + t) * 16 + p * 2 + 1];
        }
        float mean = s0 * (1.f / 65536.f);
        float var = s1 * (1.f / 65536.f) - mean * mean;
        gs[2 * t] = mean;
        gs[2 * t + 1] = rsqrtf(var + 1e-5f);
    }
    __syncthreads();
    {
        int col = t & 15, crow = t >> 4;
#pragma unroll
        for (int p = 0; p < 16; p++) {
            int c = p * 16 + crow;
            int g = c >> 6;
            float sc = gs[g * 2 + 1] * gnw[c];
            float bs = gnb[c] - gs[g * 2] * sc;
            float4 v = *(const float4*)(x + ((size_t)b * 256 + c) * 1024 + n0 + col * 4);
            int nl = col * 4;
            xl[(nl + 0) * 264 + c] = (unsigned short)(bfbits(fmaf(v.x, sc, bs)) >> 16);
            xl[(nl + 1) * 264 + c] = (unsigned short)(bfbits(fmaf(v.y, sc, bs)) >> 16);
            xl[(nl + 2) * 264 + c] = (unsigned short)(bfbits(fmaf(v.z, sc, bs)) >> 16);
            xl[(nl + 3) * 264 + c] = (unsigned short)(bfbits(fmaf(v.w, sc, bs)) >> 16);
        }
    }
    __syncthreads();
    int wm = (w >> 1) * 64, wn = (w & 1) * 32;
    int mbase = half * 128 + wm;
    int bh = b * 2 + half;
    f32x4 aq[4][2] = {}, akk[4][2] = {}, av[4][2] = {};
#pragma unroll
    for (int k = 0; k < 256; k += 32) {
        bf16x8 bfr[2];
#pragma unroll
        for (int i = 0; i < 2; i++)
            bfr[i] = *(const bf16x8*)&xl[(wn + i * 16 + c4) * 264 + k + quad * 8];
#pragma unroll
        for (int mi = 0; mi < 4; mi++) {
            bf16x8 afq = *(const bf16x8*)(wqb + (mbase + mi * 16 + c4) * 256 + k + quad * 8);
            bf16x8 afk = *(const bf16x8*)(wkb + (mbase + mi * 16 + c4) * 256 + k + quad * 8);
            bf16x8 afv = *(const bf16x8*)(wvb + (mbase + mi * 16 + c4) * 256 + k + quad * 8);
#pragma unroll
            for (int ni = 0; ni < 2; ni++) {
                aq[mi][ni]  = __builtin_amdgcn_mfma_f32_16x16x32_bf16(afq, bfr[ni], aq[mi][ni], 0, 0, 0);
                akk[mi][ni] = __builtin_amdgcn_mfma_f32_16x16x32_bf16(afk, bfr[ni], akk[mi][ni], 0, 0, 0);
                av[mi][ni]  = __builtin_amdgcn_mfma_f32_16x16x32_bf16(afv, bfr[ni], av[mi][ni], 0, 0, 0);
            }
        }
    }
    __syncthreads();
#pragma unroll
    for (int mi = 0; mi < 4; mi++)
#pragma unroll
        for (int ni = 0; ni < 2; ni++) {
            int row = wn + ni * 16 + c4;          // i-local
            int col = wm + mi * 16 + quad * 4;    // ch
            uint2 uq, uk;
            uq.x = packbf(aq[mi][ni][0], aq[mi][ni][1]);
            uq.y = packbf(aq[mi][ni][2], aq[mi][ni][3]);
            uk.x = packbf(akk[mi][ni][0], akk[mi][ni][1]);
            uk.y = packbf(akk[mi][ni][2], akk[mi][ni][3]);
            *(uint2*)&xl[row * 136 + col] = uq;
            *(uint2*)&xl[8704 + row * 136 + col] = uk;
#pragma unroll
            for (int r = 0; r < 4; r++)
                ebuf[(col + r) * 72 + row] = f2bf(av[mi][ni][r]);
        }
    __syncthreads();
#pragma unroll
    for (int p = 0; p < 4; p++) {
        int i = p * 16 + (t >> 4), off = (t & 15) * 8;
        *(bf16x8*)(qt + ((size_t)bh * 1024 + n0 + i) * 128 + off) =
            *(const bf16x8*)&xl[i * 136 + off];
        *(bf16x8*)(kt + ((size_t)bh * 1024 + n0 + i) * 128 + off) =
            *(const bf16x8*)&xl[8704 + i * 136 + off];
    }
#pragma unroll
    for (int p = 0; p < 4; p++) {
        int ch = p * 32 + (t >> 3), off = (t & 7) * 8;
        *(bf16x8*)(vv + ((size_t)bh * 128 + ch) * 1024 + n0 + off) =
            *(const bf16x8*)&ebuf[ch * 72 + off];
    }
}

// ------------------------------------------------------ flash attention v11
// 16x16x32 MFMA, LDS-staged, grid 1024 (32-row q-tiles), 48 KB LDS ->
// 3 blocks/CU. 4 waves = (qh: 16 q-rows) x (jh: 32-of-64 j). Per jt:
// B1 -> stage V(jt) + prefetch K(jt+1) -> S^T from K[cur] -> softmax ->
// B2 (V visible) -> PV. End: 2-way jh merge through LDS. No online max.
__global__ __launch_bounds__(256, 3) void attn_kernel(const unsigned short* __restrict__ qt,
                                                      const unsigned short* __restrict__ kt,
                                                      const unsigned short* __restrict__ vv,
                                                      unsigned short* __restrict__ ot) {
    int L = blockIdx.x;
    int xcd = L & 7, jj = L >> 3;           // jj in [0,128)
    int bh = (jj >> 5) * 8 + xcd;           // 4 bh per XCD (K/V L2-resident)
    int qb = jj & 31;                       // 32-row q-tile
    int b = bh >> 1, h = bh & 1;
    int tid = threadIdx.x, w = tid >> 6, lane = tid & 63;
    int quad = lane >> 4, c4 = lane & 15;
    int qh = w & 1, jh = w >> 1;
    __shared__ __align__(16) unsigned short klds[2][8192];   // 2 x 16 KB K dbuf
    __shared__ __align__(16) unsigned short vlds[8192];      // 16 KB V single

    const unsigned short* qp = qt + (size_t)bh * 1024 * 128;
    const unsigned short* kp = kt + (size_t)bh * 1024 * 128;
    const unsigned short* vp = vv + (size_t)bh * 128 * 1024;
    int i0 = qb * 32 + qh * 16;

    // Q B-frags (16 rows) kept in regs: i = i0 + c4, k = kk*32 + quad*8
    bf16x8 bq[4];
#pragma unroll
    for (int kk = 0; kk < 4; kk++)
        bq[kk] = *(const bf16x8*)(qp + (size_t)(i0 + c4) * 128 + kk * 32 + quad * 8);

    float lsum = 0.f;        // partial row-sum for i = i0 + c4 (dup x4 quads)
    f32x4 oacc[8] = {};      // O[i = quad*4+r][c = n*16 + c4]

    // ---- prime: stage K(0) into klds[0] (16 chunks of 1KB, 4 per wave)
#pragma unroll
    for (int t = 0; t < 4; t++) {
        int chunk = w * 4 + t;
        int np = chunk >> 2, kk = chunk & 3;
        gload_lds16(kp + (size_t)(np * 16 + c4) * 128 + kk * 32 + quad * 8,
                    &klds[0][chunk * 512]);
    }

    for (int jt = 0; jt < 16; jt++) {
        int cur = jt & 1;
        int j0 = jt * 64;
        __syncthreads();   // B1: K(cur) visible; V(jt-1)/K-next-buf reads done
        // ---- stage V(jt) into single buffer (16 chunks, 4/wave)
#pragma unroll
        for (int t = 0; t < 4; t++) {
            int chunk = w * 4 + t;
            int n = chunk >> 1, kw = chunk & 1;
            gload_lds16(vp + (size_t)(n * 16 + c4) * 1024 + j0 + kw * 32 + quad * 8,
                        &vlds[chunk * 512]);
        }
        // ---- prefetch K(jt+1) into the other K buffer
        if (jt < 15) {
            int j0n = j0 + 64, nb = cur ^ 1;
#pragma unroll
            for (int t = 0; t < 4; t++) {
                int chunk = w * 4 + t;
                int np = chunk >> 2, kk = chunk & 3;
                gload_lds16(kp + (size_t)(j0n + np * 16 + c4) * 128 + kk * 32 + quad * 8,
                            &klds[nb][chunk * 512]);
            }
        }

        // ---- S^T for this wave's j-half: st[npl], j = j0 + (jh*2+npl)*16 + quad*4 + r
        f32x4 st[2] = {};
#pragma unroll
        for (int npl = 0; npl < 2; npl++)
#pragma unroll
            for (int kk = 0; kk < 4; kk++) {
                bf16x8 ak = *(const bf16x8*)&klds[cur][((jh * 2 + npl) * 4 + kk) * 512 + lane * 8];
                st[npl] = __builtin_amdgcn_mfma_f32_16x16x32_bf16(ak, bq[kk], st[npl], 0, 0, 0);
            }

        // ---- p = exp2(s) (log2e folded into wq); accumulate row sums
#pragma unroll
        for (int npl = 0; npl < 2; npl++)
#pragma unroll
            for (int r = 0; r < 4; r++) {
                float p = exp2f(st[npl][r]);
                st[npl][r] = p;
                lsum += p;
            }
        // ---- pack pair (np0, np1): pk2[r]
        unsigned pk2[4];
#pragma unroll
        for (int r = 0; r < 4; r++)
            pk2[r] = packtr(st[0][r], st[1][r]);

        __syncthreads();   // B2: V(jt) visible (K prefetch pre-drained too)

        // ---- P re-frag via shfl (R3-proven, kw := jh) + PV over 32 j
        int sbase = ((lane & 16) ? 32 : 0) + c4;
        bool hi = (lane & 32) != 0;
        bf16x8 pa;
#pragma unroll
        for (int t = 0; t < 4; t++) {
            unsigned u  = (unsigned)__shfl((int)pk2[t], sbase);
            unsigned u2 = (unsigned)__shfl((int)pk2[t], sbase + 16);
            pa[t]     = (short)(hi ? (u >> 16)  : (u & 0xffffu));
            pa[4 + t] = (short)(hi ? (u2 >> 16) : (u2 & 0xffffu));
        }
#pragma unroll
        for (int n = 0; n < 8; n++) {
            bf16x8 bv = *(const bf16x8*)&vlds[(n * 2 + jh) * 512 + lane * 8];
            oacc[n] = __builtin_amdgcn_mfma_f32_16x16x32_bf16(pa, bv, oacc[n], 0, 0, 0);
        }
    }

    // ---- finish row sums (reduce over quads)
    lsum += __shfl_xor(lsum, 16);
    lsum += __shfl_xor(lsum, 32);

    // ---- merge jh halves (waves w and w^2) through LDS
    __syncthreads();
    float* mf = (float*)klds;   // 2 x 16x128 fp32 = 16 KB
    float* sf = (float*)vlds;
    if (jh == 1) {
#pragma unroll
        for (int n = 0; n < 8; n++)
            *(f32x4*)&mf[(qh * 16 + n * 2 + (lane >> 5)) * 128 +
                         ((lane >> 4) & 1) * 64 + c4 * 4] = oacc[n];
        // simpler unique slot per (n, quad, c4): use linear layout instead
        sf[qh * 16 + c4] = lsum;   // all quads same value; benign dup write
    }
    __syncthreads();
    if (jh == 0) {
        // read partner's oacc: partner wave had same (quad,c4) mapping; its
        // element (n, r) lives at the slot IT wrote. Recompute that address.
#pragma unroll
        for (int n = 0; n < 8; n++) {
            f32x4 o2 = *(const f32x4*)&mf[(qh * 16 + n * 2 + (lane >> 5)) * 128 +
                                          ((lane >> 4) & 1) * 64 + c4 * 4];
            oacc[n] += o2;
        }
        lsum += sf[qh * 16 + c4];
        float inv = 1.0f / lsum;
        float ir[4];
#pragma unroll
        for (int r = 0; r < 4; r++) ir[r] = __shfl(inv, quad * 4 + r);
#pragma unroll
        for (int n = 0; n < 8; n++)
#pragma unroll
            for (int r = 0; r < 4; r++) {
                int i = i0 + quad * 4 + r;
                int c = h * 128 + n * 16 + c4;
                ot[((size_t)b * 1024 + i) * 256 + c] = f2bf(oacc[n][r] * ir[r]);
            }
    }
}

// ------------------------------------------------------ proj + residual
__global__ __launch_bounds__(256) void proj_gemm(const unsigned short* __restrict__ wpb,
                                                 const unsigned short* __restrict__ ot,
                                                 const float* __restrict__ x,
                                                 float* __restrict__ out) {
    int b = blockIdx.z;
    int my = blockIdx.y;   // 0..1
    int nx = blockIdx.x;   // 0..15
    int tid = threadIdx.x;
    int w = tid >> 6, lane = tid & 63, quad = lane >> 4, c4 = lane & 15;
    int wm = (w >> 1) * 64, wn = (w & 1) * 32;
    int mbase = my * 128 + wm;
    int nbase = nx * 64 + wn;
    const unsigned short* ob = ot + (size_t)b * 1024 * 256;

    f32x4 acc[4][2] = {};
#pragma unroll
    for (int k = 0; k < 256; k += 32) {
        bf16x8 af[4], bfr[2];
#pragma unroll
        for (int i = 0; i < 4; i++)
            af[i] = *(const bf16x8*)(wpb + (mbase + i * 16 + c4) * 256 + k + quad * 8);
#pragma unroll
        for (int i = 0; i < 2; i++)
            bfr[i] = *(const bf16x8*)(ob + (size_t)(nbase + i * 16 + c4) * 256 + k + quad * 8);
#pragma unroll
        for (int mi = 0; mi < 4; mi++)
#pragma unroll
            for (int ni = 0; ni < 2; ni++)
                acc[mi][ni] = __builtin_amdgcn_mfma_f32_16x16x32_bf16(
                    af[mi], bfr[ni], acc[mi][ni], 0, 0, 0);
    }
#pragma unroll
    for (int mi = 0; mi < 4; mi++)
#pragma unroll
        for (int ni = 0; ni < 2; ni++)
#pragma unroll
            for (int r = 0; r < 4; r++) {
                int o = mbase + mi * 16 + quad * 4 + r;
                int i = nbase + ni * 16 + c4;
                size_t idx = ((size_t)b * 256 + o) * 1024 + i;
                out[idx] = acc[mi][ni][r] + x[idx];
            }
}

// ---------------------------------------------------------------------------
extern "C" void kernel_launch(void* const* d_in, const int* in_sizes, int n_in,
                              void* d_out, int out_size, void* d_ws, size_t ws_size,
                              hipStream_t stream) {
    const float* x   = (const float*)d_in[0];
    const float* gnw = (const float*)d_in[1];
    const float* gnb = (const float*)d_in[2];
    const float* wq  = (const float*)d_in[3];
    const float* wk  = (const float*)d_in[4];
    const float* wv  = (const float*)d_in[5];
    const float* wp  = (const float*)d_in[6];
    float* out = (float*)d_out;

    char* ws = (char*)d_ws;
    float* acc = (float*)ws;                                        //   4 KiB
    unsigned short* wqb = (unsigned short*)(ws + 4096);             // 128 KiB each
    unsigned short* wkb = (unsigned short*)(ws + 4096 + 131072);
    unsigned short* wvb = (unsigned short*)(ws + 4096 + 2 * 131072);
    unsigned short* wpb = (unsigned short*)(ws + 4096 + 3 * 131072);
    size_t base = 4096 + 4 * 131072;
    const size_t SZ = (size_t)16 * 1024 * 256 * 2;  // 8 MiB each
    unsigned short* qt = (unsigned short*)(ws + base);
    unsigned short* kt = (unsigned short*)(ws + base + SZ);
    unsigned short* vv = (unsigned short*)(ws + base + 2 * SZ);
    unsigned short* ot = (unsigned short*)(ws + base + 3 * SZ);

    prep<<<768, 256, 0, stream>>>(wq, wk, wv, wp, wqb, wkb, wvb, wpb, x, acc);
    qkv_fused<<<dim3(16, 2, 16), 256, 0, stream>>>(x, acc, gnw, gnb,
                                                   wqb, wkb, wvb, qt, kt, vv);
    attn_kernel<<<1024, 256, 0, stream>>>(qt, kt, vv, ot);
    proj_gemm<<<dim3(16, 2, 16), 256, 0, stream>>>(wpb, ot, x, out);
}